// Round 1
// baseline (10341.377 us; speedup 1.0000x reference)
//
#include <hip/hip_runtime.h>
#include <math.h>

#define B   32
#define H   1024
#define EMB 512
#define V   32000
#define SOS 1

// ws layout (floats): xT[EMB*B] | hA[H*B] | hB[H*B]
// xT[k*B+b] = tanh(embedding[tok_b][k]);  h*[j*B+b] = hidden state (transposed)

// ---------------------------------------------------------------- INIT
__global__ void k_init(const float* __restrict__ init_hidden,
                       const float* __restrict__ emb,
                       float* __restrict__ xT, float* __restrict__ hT)
{
    int idx = blockIdx.x * blockDim.x + threadIdx.x;
    int stride = gridDim.x * blockDim.x;
    for (int i = idx; i < EMB * B; i += stride) {
        int k = i / B;
        xT[i] = tanhf(emb[(size_t)SOS * EMB + k]);   // same for all b
    }
    for (int i = idx; i < H * B; i += stride) {
        int j = i / B, b = i % B;
        hT[j * B + b] = init_hidden[b * H + j];
    }
}

// ---------------------------------------------------------------- GRU (gates + h update, fused)
// 512 blocks x 256 thr. Block handles j' in {2*bi, 2*bi+1} -> rows l = g*2+jj (g=gate r/z/n).
// Thread: b = t&31, ks = t>>5 (8 k-slices of 192 over K = 512(x) + 1024(h)).
__global__ __launch_bounds__(256) void k_gru(
    const float* __restrict__ xT, const float* __restrict__ hTo,
    const float* __restrict__ wih, const float* __restrict__ bih,
    const float* __restrict__ whh, const float* __restrict__ bhh,
    float* __restrict__ hTn)
{
    const int t  = threadIdx.x;
    const int b  = t & 31;
    const int ks = t >> 5;
    const int jb = blockIdx.x * 2;

    float ai[6], ah[6];
#pragma unroll
    for (int l = 0; l < 6; ++l) { ai[l] = 0.f; ah[l] = 0.f; }

    const int k0 = ks * 192, k1 = k0 + 192;

    // x-part: k in [k0,k1) ∩ [0,EMB)
    const int xe = (k1 < EMB) ? k1 : EMB;
    for (int k = k0; k < xe; k += 4) {
        float u0 = xT[(k + 0) * B + b];
        float u1 = xT[(k + 1) * B + b];
        float u2 = xT[(k + 2) * B + b];
        float u3 = xT[(k + 3) * B + b];
#pragma unroll
        for (int l = 0; l < 6; ++l) {
            const int row = (l >> 1) * H + jb + (l & 1);
            const float4 w = *(const float4*)&wih[(size_t)row * EMB + k];
            ai[l] = fmaf(w.x, u0, ai[l]);
            ai[l] = fmaf(w.y, u1, ai[l]);
            ai[l] = fmaf(w.z, u2, ai[l]);
            ai[l] = fmaf(w.w, u3, ai[l]);
        }
    }
    // h-part: k in [k0,k1) ∩ [EMB, EMB+H)
    const int hs = (k0 > EMB) ? k0 : EMB;
    for (int k = hs; k < k1; k += 4) {
        const int kh = k - EMB;
        float u0 = hTo[(kh + 0) * B + b];
        float u1 = hTo[(kh + 1) * B + b];
        float u2 = hTo[(kh + 2) * B + b];
        float u3 = hTo[(kh + 3) * B + b];
#pragma unroll
        for (int l = 0; l < 6; ++l) {
            const int row = (l >> 1) * H + jb + (l & 1);
            const float4 w = *(const float4*)&whh[(size_t)row * H + kh];
            ah[l] = fmaf(w.x, u0, ah[l]);
            ah[l] = fmaf(w.y, u1, ah[l]);
            ah[l] = fmaf(w.z, u2, ah[l]);
            ah[l] = fmaf(w.w, u3, ah[l]);
        }
    }

    __shared__ float red[6 * 32 * 8];
    __shared__ float Gi[6 * 32], Gh[6 * 32];

#pragma unroll
    for (int l = 0; l < 6; ++l) red[(l * 32 + b) * 8 + ks] = ai[l];
    __syncthreads();
    for (int o = t; o < 192; o += 256) {
        float s = 0.f;
#pragma unroll
        for (int q = 0; q < 8; ++q) s += red[o * 8 + q];
        Gi[o] = s;
    }
    __syncthreads();
#pragma unroll
    for (int l = 0; l < 6; ++l) red[(l * 32 + b) * 8 + ks] = ah[l];
    __syncthreads();
    for (int o = t; o < 192; o += 256) {
        float s = 0.f;
#pragma unroll
        for (int q = 0; q < 8; ++q) s += red[o * 8 + q];
        Gh[o] = s;
    }
    __syncthreads();

    if (t < 64) {
        const int jj = t >> 5, bb = t & 31;
        const int row = jb + jj;
        float gir = Gi[(0 * 2 + jj) * 32 + bb] + bih[row];
        float ghr = Gh[(0 * 2 + jj) * 32 + bb] + bhh[row];
        float giz = Gi[(1 * 2 + jj) * 32 + bb] + bih[H + row];
        float ghz = Gh[(1 * 2 + jj) * 32 + bb] + bhh[H + row];
        float gin = Gi[(2 * 2 + jj) * 32 + bb] + bih[2 * H + row];
        float ghn = Gh[(2 * 2 + jj) * 32 + bb] + bhh[2 * H + row];
        float r = 1.f / (1.f + expf(-(gir + ghr)));
        float z = 1.f / (1.f + expf(-(giz + ghz)));
        float n = tanhf(gin + r * ghn);          // r multiplies only the hh part (incl. b_hh)
        float ho = hTo[row * B + bb];
        hTn[row * B + bb] = (1.f - z) * n + z * ho;
    }
}

// ---------------------------------------------------------------- PROJ (raw logits -> d_out[t])
// 500 blocks x 256 thr. 64 rows/block. rs = t&63 (row), bq = t>>6 (b-quarter, 8 b).
// W staged to LDS (XOR-swizzled, double-buffered); h read via wave-uniform float4 loads.
#define PR 64
#define KC 32

__global__ __launch_bounds__(256) void k_proj(
    const float* __restrict__ hT, const float* __restrict__ wout,
    const float* __restrict__ bout, float* __restrict__ out)
{
    const int t  = threadIdx.x;
    const int rs = t & 63;
    const int bq = __builtin_amdgcn_readfirstlane(t >> 6);   // 0..3, wave-uniform
    const int r0 = blockIdx.x * PR;

    __shared__ __align__(16) float wl[2][PR * KC];

    float acc[8];
#pragma unroll
    for (int i = 0; i < 8; ++i) acc[i] = 0.f;

    const float* hTq = hT + bq * 8;

    const int Q0 = t, Q1 = t + 256;
    const int ra = Q0 >> 3, qa = Q0 & 7;
    const int rb = Q1 >> 3, qb = Q1 & 7;
    const int wa = ra * KC + 4 * (qa ^ (ra & 7));
    const int wb = rb * KC + 4 * (qb ^ (rb & 7));

    float4 sA, sB;
    // prologue: stage chunk 0
    sA = *(const float4*)&wout[(size_t)(r0 + ra) * H + 4 * qa];
    sB = *(const float4*)&wout[(size_t)(r0 + rb) * H + 4 * qb];
    *(float4*)&wl[0][wa] = sA;
    *(float4*)&wl[0][wb] = sB;
    __syncthreads();

    const int NC = H / KC;   // 32 chunks
    for (int c = 0; c < NC; ++c) {
        const int cur = c & 1;
        if (c + 1 < NC) {
            sA = *(const float4*)&wout[(size_t)(r0 + ra) * H + (c + 1) * KC + 4 * qa];
            sB = *(const float4*)&wout[(size_t)(r0 + rb) * H + (c + 1) * KC + 4 * qb];
        }
        const int kb = c * KC;
#pragma unroll
        for (int kq = 0; kq < KC / 4; ++kq) {
            const float4 w = *(const float4*)&wl[cur][rs * KC + 4 * (kq ^ (rs & 7))];
#pragma unroll
            for (int j = 0; j < 4; ++j) {
                const float wv = (j == 0) ? w.x : (j == 1) ? w.y : (j == 2) ? w.z : w.w;
                const float* up = hTq + (kb + kq * 4 + j) * B;
                const float4 ua = *(const float4*)up;
                const float4 ub = *(const float4*)(up + 4);
                acc[0] = fmaf(wv, ua.x, acc[0]);
                acc[1] = fmaf(wv, ua.y, acc[1]);
                acc[2] = fmaf(wv, ua.z, acc[2]);
                acc[3] = fmaf(wv, ua.w, acc[3]);
                acc[4] = fmaf(wv, ub.x, acc[4]);
                acc[5] = fmaf(wv, ub.y, acc[5]);
                acc[6] = fmaf(wv, ub.z, acc[6]);
                acc[7] = fmaf(wv, ub.w, acc[7]);
            }
        }
        if (c + 1 < NC) {
            *(float4*)&wl[cur ^ 1][wa] = sA;
            *(float4*)&wl[cur ^ 1][wb] = sB;
        }
        __syncthreads();
    }

    const float bo = bout[r0 + rs];
#pragma unroll
    for (int i = 0; i < 8; ++i)
        out[(size_t)(bq * 8 + i) * V + (r0 + rs)] = acc[i] + bo;
}

// ---------------------------------------------------------------- FIN (log-softmax in-place + argmax + next embed)
__global__ __launch_bounds__(256) void k_fin(
    float* __restrict__ out /* t-slice */, const float* __restrict__ emb,
    float* __restrict__ xT)
{
    const int b = blockIdx.x;
    const int t = threadIdx.x;
    float* row = out + (size_t)b * V;

    __shared__ float sv[256];
    __shared__ int   si[256];
    __shared__ float sr[256];

    float m = -3.0e38f; int mi = 0;
    for (int v = t; v < V; v += 256) {
        float x = row[v];
        if (x > m) { m = x; mi = v; }
    }
    sv[t] = m; si[t] = mi;
    __syncthreads();
    for (int s = 128; s > 0; s >>= 1) {
        if (t < s) {
            float ov = sv[t + s]; int oi = si[t + s];
            if (ov > sv[t] || (ov == sv[t] && oi < si[t])) { sv[t] = ov; si[t] = oi; }
        }
        __syncthreads();
    }
    const float M = sv[0];

    float acc = 0.f;
    for (int v = t; v < V; v += 256) acc += expf(row[v] - M);
    sr[t] = acc;
    __syncthreads();
    for (int s = 128; s > 0; s >>= 1) {
        if (t < s) sr[t] += sr[t + s];
        __syncthreads();
    }
    const float C = M + logf(sr[0]);
    const int TOK = si[0];

    for (int v = t; v < V; v += 256) row[v] -= C;

    for (int k = t; k < EMB; k += 256)
        xT[k * B + b] = tanhf(emb[(size_t)TOK * EMB + k]);
}

// ---------------------------------------------------------------- launch
extern "C" void kernel_launch(void* const* d_in, const int* in_sizes, int n_in,
                              void* d_out, int out_size, void* d_ws, size_t ws_size,
                              hipStream_t stream)
{
    const float* init_hidden = (const float*)d_in[0];
    // d_in[1] encoder_outputs: unused by the reference
    // d_in[2] tgt_len: recovered from out_size instead
    const float* emb  = (const float*)d_in[3];
    const float* wih  = (const float*)d_in[4];
    const float* bih  = (const float*)d_in[5];
    const float* whh  = (const float*)d_in[6];
    const float* bhh  = (const float*)d_in[7];
    const float* wout = (const float*)d_in[8];
    const float* bout = (const float*)d_in[9];
    float* out = (float*)d_out;

    const int T = out_size / (B * V);   // 64

    float* ws = (float*)d_ws;
    float* xT = ws;                 // EMB*B
    float* hA = xT + EMB * B;       // H*B
    float* hB = hA + H * B;         // H*B

    k_init<<<64, 256, 0, stream>>>(init_hidden, emb, xT, hA);

    for (int t = 0; t < T; ++t) {
        const float* hold = (t & 1) ? hB : hA;
        float*       hnew = (t & 1) ? hA : hB;
        k_gru<<<H / 2, 256, 0, stream>>>(xT, hold, wih, bih, whh, bhh, hnew);
        k_proj<<<V / PR, 256, 0, stream>>>(hnew, wout, bout, out + (size_t)t * B * V);
        k_fin<<<B, 256, 0, stream>>>(out + (size_t)t * B * V, emb, xT);
    }
}